// Round 4
// baseline (813.844 us; speedup 1.0000x reference)
//
#include <hip/hip_runtime.h>
#include <hip/hip_bf16.h>

#define N_TOK 2048
#define H_DIM 2048
#define V_DIM 32000

typedef __attribute__((ext_vector_type(8))) short short8;
typedef __attribute__((ext_vector_type(4))) short s16x4;
typedef __attribute__((ext_vector_type(16))) float f32x16;

__device__ __forceinline__ float bf2f(short s) {
  unsigned int u = ((unsigned int)(unsigned short)s) << 16;
  return __uint_as_float(u);
}
__device__ __forceinline__ short f2b(float f) {
  __hip_bfloat16 h = __float2bfloat16(f);
  return *reinterpret_cast<short*>(&h);
}

// ---------------- fp32 -> bf16 conversion (vectorized, grid-stride) -------
__global__ __launch_bounds__(256) void cvt_bf16(const float* __restrict__ s,
                                                short* __restrict__ d, int n8) {
  int stride = gridDim.x * 256;
  for (int i = blockIdx.x * 256 + threadIdx.x; i < n8; i += stride) {
    const float4* sp = reinterpret_cast<const float4*>(s) + (size_t)i * 2;
    float4 a = sp[0], b = sp[1];
    short8 o;
    o[0] = f2b(a.x); o[1] = f2b(a.y); o[2] = f2b(a.z); o[3] = f2b(a.w);
    o[4] = f2b(b.x); o[5] = f2b(b.y); o[6] = f2b(b.z); o[7] = f2b(b.w);
    *reinterpret_cast<short8*>(d + (size_t)i * 8) = o;
  }
}

// ---------------- bf16 GEMM: logits[n,v] = sum_h A[n,h]*W[v,h] ------------
// BM=BN=256, BK=64, 8 waves (2M x 4N), wave tile 128x64, MFMA 32x32x16.
// LDS: 2 buffers x (A 256x64 + B 256x64) bf16 = 128 KiB, XOR-swizzled via
// pre-swizzled global source (rule 21). Shifted staging: B+A-hi of tile t+1
// issued in P1/P2 of t, A-lo of tile t+2 into the CURRENT buffer in P4 (its
// regions were last read in P3, whose lgkmcnt(0)+barrier precede P4). One
// counted vmcnt(2) gate per tile -> every load gets a >=2-phase window.
#define ASH 16384      // A shorts per buffer (256 rows x 64 cols)
#define BUF_SH 32768   // shorts per buffer (A + B)

__device__ __forceinline__ void gload_lds16(const void* g, void* l) {
  __builtin_amdgcn_global_load_lds(
      (const __attribute__((address_space(1))) void*)g,
      (__attribute__((address_space(3))) void*)l, 16, 0, 0);
}

#define STAGE_A(i, dst, kb) \
  gload_lds16(Aby + aoff##i + (kb), &lds[(dst) + (i) * 4096 + wbase])
#define STAGE_B(i, dst, kb) \
  gload_lds16(Wby + boff##i + (kb), &lds[(dst) + ASH + (i) * 4096 + wbase])

#define MFMA32(a, b, c) __builtin_amdgcn_mfma_f32_32x32x16_bf16(a, b, c, 0, 0, 0)

// Phase (KS2 = k-step pair 0/1, MH = m-half 0/1): ds_read fragments, issue
// staging (__VA_ARGS__), barrier, lgkmcnt(0), 8 MFMA under setprio, optional
// vmcnt gate (2 = counted steady state, 0 = tail drain), barrier.
#define PHASE(KS2, MH, GATE, ...) do {                                         \
    short8 a00 = *(const short8*)&lds[cbase + aroA + ((MH)*2+0)*2048 + gx[(KS2)*2]];   \
    short8 a01 = *(const short8*)&lds[cbase + aroA + ((MH)*2+0)*2048 + gx[(KS2)*2+1]]; \
    short8 a10 = *(const short8*)&lds[cbase + aroA + ((MH)*2+1)*2048 + gx[(KS2)*2]];   \
    short8 a11 = *(const short8*)&lds[cbase + aroA + ((MH)*2+1)*2048 + gx[(KS2)*2+1]]; \
    if ((MH) == 0) {                                                           \
      bv00 = *(const short8*)&lds[cbase + broB + 0    + gx[(KS2)*2]];          \
      bv01 = *(const short8*)&lds[cbase + broB + 0    + gx[(KS2)*2+1]];        \
      bv10 = *(const short8*)&lds[cbase + broB + 2048 + gx[(KS2)*2]];          \
      bv11 = *(const short8*)&lds[cbase + broB + 2048 + gx[(KS2)*2+1]];        \
    }                                                                          \
    __VA_ARGS__                                                                \
    __builtin_amdgcn_sched_barrier(0);                                         \
    __builtin_amdgcn_s_barrier();                                              \
    asm volatile("s_waitcnt lgkmcnt(0)" ::: "memory");                         \
    __builtin_amdgcn_sched_barrier(0);                                         \
    __builtin_amdgcn_s_setprio(1);                                             \
    acc[(MH)*2+0][0] = MFMA32(a00, bv00, acc[(MH)*2+0][0]);                    \
    acc[(MH)*2+0][0] = MFMA32(a01, bv01, acc[(MH)*2+0][0]);                    \
    acc[(MH)*2+0][1] = MFMA32(a00, bv10, acc[(MH)*2+0][1]);                    \
    acc[(MH)*2+0][1] = MFMA32(a01, bv11, acc[(MH)*2+0][1]);                    \
    acc[(MH)*2+1][0] = MFMA32(a10, bv00, acc[(MH)*2+1][0]);                    \
    acc[(MH)*2+1][0] = MFMA32(a11, bv01, acc[(MH)*2+1][0]);                    \
    acc[(MH)*2+1][1] = MFMA32(a10, bv10, acc[(MH)*2+1][1]);                    \
    acc[(MH)*2+1][1] = MFMA32(a11, bv11, acc[(MH)*2+1][1]);                    \
    __builtin_amdgcn_s_setprio(0);                                             \
    if ((GATE) == 2) asm volatile("s_waitcnt vmcnt(2)" ::: "memory");          \
    if ((GATE) == 0) asm volatile("s_waitcnt vmcnt(0)" ::: "memory");          \
    __builtin_amdgcn_sched_barrier(0);                                         \
    __builtin_amdgcn_s_barrier();                                              \
  } while (0)

__global__ __launch_bounds__(512, 2) void gemm_logits(
    const short* __restrict__ As, const short* __restrict__ At,
    const short* __restrict__ Ws, const short* __restrict__ Wt,
    unsigned long long* __restrict__ Lgs, unsigned long long* __restrict__ Lgt) {
  __shared__ short lds[2 * BUF_SH];  // 128 KiB

  // Bijective XCD chunking (2000 % 8 == 0), mblk-fastest: 8 consecutive
  // blocks share one 1 MB W panel (L2-hot); W streams HBM once; A in LLC.
  const int gid = blockIdx.x;
  const int swz = (gid & 7) * 250 + (gid >> 3);
  const int gemm = swz >= 1000;
  const int rem = swz - gemm * 1000;
  const int vblk = rem >> 3, mblk = rem & 7;
  const short* A = gemm ? At : As;
  const short* W = gemm ? Wt : Ws;
  unsigned long long* Lp = gemm ? Lgt : Lgs;
  const int m0 = mblk * 256, v0 = vblk * 256;

  const int tid = threadIdx.x;
  const int wave = tid >> 6, lane = tid & 63;
  const int lane31 = lane & 31, hi5 = lane >> 5, l7 = lane31 & 7;
  const int wr = wave >> 2, wc = wave & 3;   // 2M x 4N wave grid
  const int wbase = wave * 512;              // gload LDS granule base (shorts)
  const int aroA = (wr * 128 + lane31) * 64; // A ds_read row base (shorts)
  const int broB = ASH + (wc * 64 + lane31) * 64;
  const char* Aby = (const char*)A;
  const char* Wby = (const char*)W;

  // k-granule byte columns for the 4 k-steps (XOR-swizzled; row&7 == lane31&7
  // for all fragments since fm/fn/wr/wc offsets are multiples of 8 rows).
  int gx[4];
#pragma unroll
  for (int k = 0; k < 4; ++k) gx[k] = ((k * 2 + hi5) ^ l7) << 3;

  // Pre-swizzled per-lane global source offsets (bytes) for the 8 loads of a
  // K-tile; per tile only kb (bytes, = t*128) advances.
  unsigned aoff0, aoff1, aoff2, aoff3, boff0, boff1, boff2, boff3;
  {
#define MKOFF(i, dstA, dstB)                                                   \
    {                                                                          \
      int g = (i) * 512 + wave * 64 + lane;                                    \
      int row = g >> 3, c8p = g & 7, col = (c8p ^ (row & 7)) << 3;             \
      dstA = (unsigned)((((m0) + row) * H_DIM + col) * 2);                     \
      dstB = (unsigned)((((v0) + row) * H_DIM + col) * 2);                     \
    }
    MKOFF(0, aoff0, boff0) MKOFF(1, aoff1, boff1)
    MKOFF(2, aoff2, boff2) MKOFF(3, aoff3, boff3)
#undef MKOFF
  }

  f32x16 acc[4][2];
  const f32x16 z16 = {0.f,0.f,0.f,0.f,0.f,0.f,0.f,0.f,
                      0.f,0.f,0.f,0.f,0.f,0.f,0.f,0.f};
#pragma unroll
  for (int i = 0; i < 4; ++i) { acc[i][0] = z16; acc[i][1] = z16; }
  short8 bv00, bv01, bv10, bv11;

  // Prologue: tile0 fully + A-lo of tile1; vmcnt(2) leaves A0,A2(t1) in flight.
  STAGE_A(0, 0, 0); STAGE_A(2, 0, 0);
  STAGE_B(0, 0, 0); STAGE_B(1, 0, 0); STAGE_B(2, 0, 0); STAGE_B(3, 0, 0);
  STAGE_A(1, 0, 0); STAGE_A(3, 0, 0);
  STAGE_A(0, BUF_SH, 128); STAGE_A(2, BUF_SH, 128);
  asm volatile("s_waitcnt vmcnt(2)" ::: "memory");
  __builtin_amdgcn_s_barrier();

  // Steady tiles 0..29. Per tile t: P1 stages B0-3(t+1)->nxt, P2 stages
  // A1,A3(t+1)->nxt, P4 stages A0,A2(t+2)->cur (rows 0-63/128-191, last read
  // in P3) and gates vmcnt(2) (only A0,A2(t+2) left in flight).
  for (int t = 0; t < 30; ++t) {
    const int cbase = (t & 1) * BUF_SH, nbase = cbase ^ BUF_SH;
    const int kbn = (t + 1) * 128, kbc = (t + 2) * 128;
    PHASE(0, 0, -1, STAGE_B(0, nbase, kbn); STAGE_B(1, nbase, kbn);
                    STAGE_B(2, nbase, kbn); STAGE_B(3, nbase, kbn););
    PHASE(0, 1, -1, STAGE_A(1, nbase, kbn); STAGE_A(3, nbase, kbn););
    PHASE(1, 0, -1, (void)0;);
    PHASE(1, 1,  2, STAGE_A(0, cbase, kbc); STAGE_A(2, cbase, kbc););
  }
  // Tile 30: stage rest of tile 31, drain at end.
  { const int cbase = 0, nbase = BUF_SH, kbn = 31 * 128;
    PHASE(0, 0, -1, STAGE_B(0, nbase, kbn); STAGE_B(1, nbase, kbn);
                    STAGE_B(2, nbase, kbn); STAGE_B(3, nbase, kbn););
    PHASE(0, 1, -1, STAGE_A(1, nbase, kbn); STAGE_A(3, nbase, kbn););
    PHASE(1, 0, -1, (void)0;);
    PHASE(1, 1,  0, (void)0;);
  }
  // Tile 31: no staging, no gates.
  { const int cbase = BUF_SH;
    PHASE(0, 0, -1, (void)0;);
    PHASE(0, 1, -1, (void)0;);
    PHASE(1, 0, -1, (void)0;);
    PHASE(1, 1, -1, (void)0;);
  }

  // Epilogue: pack layout. 32x32 C/D: col=lane&31, row=(reg&3)+8*(reg>>2)
  // +4*(lane>>5) (m74/m101-verified). Regs 4q..4q+3 = 4 consecutive rows ->
  // one 8 B bf16 pack per (fm,fn,q); lane-consecutive addresses (coalesced).
  // Pack index = ((mblk*125+vblk)*8 + wave)*2048 + (fm*2+fn)*256 + q*64 + lane.
  const size_t pkb = ((size_t)(mblk * 125 + vblk) * 8 + wave) * 2048 + lane;
  s16x4* Lp4 = (s16x4*)Lp;
#pragma unroll
  for (int fm = 0; fm < 4; ++fm)
#pragma unroll
    for (int fn = 0; fn < 2; ++fn)
#pragma unroll
      for (int qq = 0; qq < 4; ++qq) {
        s16x4 pk;
        pk[0] = f2b(acc[fm][fn][qq * 4 + 0]);
        pk[1] = f2b(acc[fm][fn][qq * 4 + 1]);
        pk[2] = f2b(acc[fm][fn][qq * 4 + 2]);
        pk[3] = f2b(acc[fm][fn][qq * 4 + 3]);
        Lp4[pkb + (fm * 2 + fn) * 256 + qq * 64] = pk;
      }
}

// ---------------- fused logsumexp + JSD over the pack layout --------------
// Group g = 4 consecutive rows r = 4g..4g+3 (one pack's worth). Row decomp:
// mblk=r>>8, wr=(r>>7)&1, fm=(r>>5)&3, q=(r>>3)&3, hi5=(r>>2)&1, j=r&3.
// No max subtraction: |logit| <= ~7 (x,w_v ~ unit-variance dot) so
// sum(exp) <= 32000*e^7 ~ 3.5e7, comfortably inside f32.
__global__ __launch_bounds__(256) void rows_jsd(
    const unsigned long long* __restrict__ Ls,
    const unsigned long long* __restrict__ Lt,
    float* __restrict__ partials) {
  const int g = blockIdx.x, tid = threadIdx.x;
  const int mblk = g >> 6, wr = (g >> 5) & 1, fm = (g >> 3) & 3,
            q = (g >> 1) & 3, hi5 = g & 1;
  const size_t base = (size_t)mblk * 2048000 + (size_t)wr * 8192 +
                      fm * 512 + q * 64 + hi5 * 32;
  const int coff = (tid & 31) + ((tid >> 5) & 1) * 256 + ((tid >> 6) & 3) * 2048;
  const unsigned long long* ps = Ls + base + coff;
  const unsigned long long* pt = Lt + base + coff;

  float ses[4] = {0.f, 0.f, 0.f, 0.f};
  float set[4] = {0.f, 0.f, 0.f, 0.f};
  for (int vb = 0; vb < 125; ++vb) {
    unsigned long long xs = ps[(size_t)vb * 16384];
    unsigned long long xt = pt[(size_t)vb * 16384];
#pragma unroll
    for (int j = 0; j < 4; ++j) {
      ses[j] += __expf(bf2f((short)(xs >> (16 * j))));
      set[j] += __expf(bf2f((short)(xt >> (16 * j))));
    }
  }
  __shared__ float red[8][4];
  __shared__ float zz[8];
  const int wv = tid >> 6, ln = tid & 63;
#pragma unroll
  for (int c = 0; c < 8; ++c) {
    float v = (c < 4) ? ses[c] : set[c - 4];
#pragma unroll
    for (int o = 32; o; o >>= 1) v += __shfl_xor(v, o);
    if (ln == 0) red[c][wv] = v;
  }
  __syncthreads();
  if (tid < 8) zz[tid] = __logf(red[tid][0] + red[tid][1] + red[tid][2] + red[tid][3]);
  __syncthreads();
  float zq[4], zp[4];
#pragma unroll
  for (int j = 0; j < 4; ++j) { zq[j] = zz[j]; zp[j] = zz[4 + j]; }

  float acc = 0.f;
  for (int vb = 0; vb < 125; ++vb) {
    unsigned long long xs = ps[(size_t)vb * 16384];
    unsigned long long xt = pt[(size_t)vb * 16384];
#pragma unroll
    for (int j = 0; j < 4; ++j) {
      float lq = bf2f((short)(xs >> (16 * j))) - zq[j];
      float lp = bf2f((short)(xt >> (16 * j))) - zp[j];
      float qq = __expf(lq), pp = __expf(lp);
      float mm = pp + 0.5f * (qq - pp);
      float lm = __logf(mm);
      acc += 0.5f * (pp * (lp - lm)) + 0.5f * (qq * (lq - lm));
    }
  }
#pragma unroll
  for (int o = 32; o; o >>= 1) acc += __shfl_xor(acc, o);
  if (ln == 0) red[0][wv] = acc;
  __syncthreads();
  if (tid == 0) partials[g] = red[0][0] + red[0][1] + red[0][2] + red[0][3];
}

__global__ __launch_bounds__(256) void final_reduce(const float* __restrict__ partials,
                                                    int nb, float* __restrict__ out) {
  float s = 0.f;
  for (int i = threadIdx.x; i < nb; i += 256) s += partials[i];
#pragma unroll
  for (int o = 32; o; o >>= 1) s += __shfl_xor(s, o);
  __shared__ float red[4];
  if ((threadIdx.x & 63) == 0) red[threadIdx.x >> 6] = s;
  __syncthreads();
  if (threadIdx.x == 0) out[0] = (red[0] + red[1] + red[2] + red[3]) / (float)N_TOK;
}

// ---------------- launch ---------------------------------------------------
extern "C" void kernel_launch(void* const* d_in, const int* in_sizes, int n_in,
                              void* d_out, int out_size, void* d_ws, size_t ws_size,
                              hipStream_t stream) {
  const float* s_in = (const float*)d_in[0];
  const float* t_in = (const float*)d_in[1];
  const float* w_s  = (const float*)d_in[2];
  const float* w_t  = (const float*)d_in[3];
  float* out = (float*)d_out;

  char* ws = (char*)d_ws;
  size_t off = 0;
  auto alloc = [&](size_t bytes) {
    char* p = ws + off;
    off += (bytes + 255) & ~(size_t)255;
    return p;
  };
  short* Abf_s = (short*)alloc((size_t)N_TOK * H_DIM * 2);
  short* Abf_t = (short*)alloc((size_t)N_TOK * H_DIM * 2);
  short* Wbf_s = (short*)alloc((size_t)V_DIM * H_DIM * 2);
  short* Wbf_t = (short*)alloc((size_t)V_DIM * H_DIM * 2);
  unsigned long long* Lg_s = (unsigned long long*)alloc((size_t)N_TOK * V_DIM * 2);
  unsigned long long* Lg_t = (unsigned long long*)alloc((size_t)N_TOK * V_DIM * 2);
  float* partials = (float*)alloc(512 * 4);

  if (off > ws_size) {
    hipMemsetAsync(d_out, 0xFF, sizeof(float), stream);
    return;
  }

  cvt_bf16<<<512, 256, 0, stream>>>(s_in, Abf_s, N_TOK * H_DIM / 8);
  cvt_bf16<<<512, 256, 0, stream>>>(t_in, Abf_t, N_TOK * H_DIM / 8);
  cvt_bf16<<<2048, 256, 0, stream>>>(w_s, Wbf_s, V_DIM * H_DIM / 8);
  cvt_bf16<<<2048, 256, 0, stream>>>(w_t, Wbf_t, V_DIM * H_DIM / 8);

  gemm_logits<<<2000, 512, 0, stream>>>(Abf_s, Abf_t, Wbf_s, Wbf_t, Lg_s, Lg_t);

  rows_jsd<<<512, 256, 0, stream>>>(Lg_s, Lg_t, partials);
  final_reduce<<<1, 256, 0, stream>>>(partials, 512, out);
}

// Round 5
// 768.833 us; speedup vs baseline: 1.0585x; 1.0585x over previous
//
#include <hip/hip_runtime.h>
#include <hip/hip_bf16.h>

#define N_TOK 2048
#define H_DIM 2048
#define V_DIM 32000

typedef __attribute__((ext_vector_type(8))) short short8;
typedef __attribute__((ext_vector_type(4))) short s16x4;
typedef __attribute__((ext_vector_type(4))) float f32x4;

__device__ __forceinline__ float bf2f(short s) {
  unsigned int u = ((unsigned int)(unsigned short)s) << 16;
  return __uint_as_float(u);
}
__device__ __forceinline__ short f2b(float f) {
  __hip_bfloat16 h = __float2bfloat16(f);
  return *reinterpret_cast<short*>(&h);
}

// ---------------- fp32 -> bf16 conversion (vectorized, grid-stride) -------
__global__ __launch_bounds__(256) void cvt_bf16(const float* __restrict__ s,
                                                short* __restrict__ d, int n8) {
  int stride = gridDim.x * 256;
  for (int i = blockIdx.x * 256 + threadIdx.x; i < n8; i += stride) {
    const float4* sp = reinterpret_cast<const float4*>(s) + (size_t)i * 2;
    float4 a = sp[0], b = sp[1];
    short8 o;
    o[0] = f2b(a.x); o[1] = f2b(a.y); o[2] = f2b(a.z); o[3] = f2b(a.w);
    o[4] = f2b(b.x); o[5] = f2b(b.y); o[6] = f2b(b.z); o[7] = f2b(b.w);
    *reinterpret_cast<short8*>(d + (size_t)i * 8) = o;
  }
}

// ---------------- bf16 GEMM: logits[n,v] = sum_h A[n,h]*W[v,h] ------------
// BM=BN=256, BK=64, 8 waves (2M x 4N), wave tile 128x64, MFMA 16x16x32
// (round-3 fragment pattern: measured 0 LDS bank conflicts).
// LDS: 2 buffers x (A 256x64 + B 256x64) bf16 = 128 KiB, XOR-swizzled via
// pre-swizzled global source (rule 21). Shifted staging: B(t+1) in P1,
// A-hi(t+1) in P2, A-lo(t+2) into the CURRENT buffer in P4 (regions last
// read in P3, whose lgkmcnt(0)+barrier precede P4). One vmcnt(2) gate per
// tile -> every load gets a >=3-phase latency window.
#define ASH 16384      // A shorts per buffer (256 rows x 64 cols)
#define BUF_SH 32768   // shorts per buffer (A + B)

__device__ __forceinline__ void gload_lds16(const void* g, void* l) {
  __builtin_amdgcn_global_load_lds(
      (const __attribute__((address_space(1))) void*)g,
      (__attribute__((address_space(3))) void*)l, 16, 0, 0);
}

#define STAGE_A(i, dst, kb) \
  gload_lds16(Aby + aoff##i + (kb), &lds[(dst) + (i) * 4096 + wbase])
#define STAGE_B(i, dst, kb) \
  gload_lds16(Wby + boff##i + (kb), &lds[(dst) + ASH + (i) * 4096 + wbase])

// Phase (KK = k-step 0/1, MH = m-half 0/1): ds_read fragments, issue staging
// (__VA_ARGS__), barrier, lgkmcnt(0), 16 MFMA under setprio, optional vmcnt
// gate (2 = counted steady state, 0 = tail drain), barrier.
#define PHASE(KK, MH, GATE, ...) do {                                          \
    const int xorc = (((KK) * 4 + lk) ^ lr7) << 3;                             \
    short8 av0 = *(const short8*)&lds[cbase + aro + (MH)*4096 + 0    + xorc];  \
    short8 av1 = *(const short8*)&lds[cbase + aro + (MH)*4096 + 1024 + xorc];  \
    short8 av2 = *(const short8*)&lds[cbase + aro + (MH)*4096 + 2048 + xorc];  \
    short8 av3 = *(const short8*)&lds[cbase + aro + (MH)*4096 + 3072 + xorc];  \
    if ((MH) == 0) {                                                           \
      bv[0] = *(const short8*)&lds[cbase + bro + 0    + xorc];                 \
      bv[1] = *(const short8*)&lds[cbase + bro + 1024 + xorc];                 \
      bv[2] = *(const short8*)&lds[cbase + bro + 2048 + xorc];                 \
      bv[3] = *(const short8*)&lds[cbase + bro + 3072 + xorc];                 \
    }                                                                          \
    __VA_ARGS__                                                                \
    __builtin_amdgcn_sched_barrier(0);                                         \
    __builtin_amdgcn_s_barrier();                                              \
    asm volatile("s_waitcnt lgkmcnt(0)" ::: "memory");                         \
    __builtin_amdgcn_sched_barrier(0);                                         \
    __builtin_amdgcn_s_setprio(1);                                             \
    acc[(MH)*4+0][0] = __builtin_amdgcn_mfma_f32_16x16x32_bf16(av0, bv[0], acc[(MH)*4+0][0],0,0,0); \
    acc[(MH)*4+0][1] = __builtin_amdgcn_mfma_f32_16x16x32_bf16(av0, bv[1], acc[(MH)*4+0][1],0,0,0); \
    acc[(MH)*4+0][2] = __builtin_amdgcn_mfma_f32_16x16x32_bf16(av0, bv[2], acc[(MH)*4+0][2],0,0,0); \
    acc[(MH)*4+0][3] = __builtin_amdgcn_mfma_f32_16x16x32_bf16(av0, bv[3], acc[(MH)*4+0][3],0,0,0); \
    acc[(MH)*4+1][0] = __builtin_amdgcn_mfma_f32_16x16x32_bf16(av1, bv[0], acc[(MH)*4+1][0],0,0,0); \
    acc[(MH)*4+1][1] = __builtin_amdgcn_mfma_f32_16x16x32_bf16(av1, bv[1], acc[(MH)*4+1][1],0,0,0); \
    acc[(MH)*4+1][2] = __builtin_amdgcn_mfma_f32_16x16x32_bf16(av1, bv[2], acc[(MH)*4+1][2],0,0,0); \
    acc[(MH)*4+1][3] = __builtin_amdgcn_mfma_f32_16x16x32_bf16(av1, bv[3], acc[(MH)*4+1][3],0,0,0); \
    acc[(MH)*4+2][0] = __builtin_amdgcn_mfma_f32_16x16x32_bf16(av2, bv[0], acc[(MH)*4+2][0],0,0,0); \
    acc[(MH)*4+2][1] = __builtin_amdgcn_mfma_f32_16x16x32_bf16(av2, bv[1], acc[(MH)*4+2][1],0,0,0); \
    acc[(MH)*4+2][2] = __builtin_amdgcn_mfma_f32_16x16x32_bf16(av2, bv[2], acc[(MH)*4+2][2],0,0,0); \
    acc[(MH)*4+2][3] = __builtin_amdgcn_mfma_f32_16x16x32_bf16(av2, bv[3], acc[(MH)*4+2][3],0,0,0); \
    acc[(MH)*4+3][0] = __builtin_amdgcn_mfma_f32_16x16x32_bf16(av3, bv[0], acc[(MH)*4+3][0],0,0,0); \
    acc[(MH)*4+3][1] = __builtin_amdgcn_mfma_f32_16x16x32_bf16(av3, bv[1], acc[(MH)*4+3][1],0,0,0); \
    acc[(MH)*4+3][2] = __builtin_amdgcn_mfma_f32_16x16x32_bf16(av3, bv[2], acc[(MH)*4+3][2],0,0,0); \
    acc[(MH)*4+3][3] = __builtin_amdgcn_mfma_f32_16x16x32_bf16(av3, bv[3], acc[(MH)*4+3][3],0,0,0); \
    __builtin_amdgcn_s_setprio(0);                                             \
    if ((GATE) == 2) asm volatile("s_waitcnt vmcnt(2)" ::: "memory");          \
    if ((GATE) == 0) asm volatile("s_waitcnt vmcnt(0)" ::: "memory");          \
    __builtin_amdgcn_sched_barrier(0);                                         \
    __builtin_amdgcn_s_barrier();                                              \
  } while (0)

__global__ __launch_bounds__(512, 2) void gemm_logits(
    const short* __restrict__ As, const short* __restrict__ At,
    const short* __restrict__ Ws, const short* __restrict__ Wt,
    unsigned long long* __restrict__ Lgs, unsigned long long* __restrict__ Lgt) {
  __shared__ short lds[2 * BUF_SH];  // 128 KiB

  // Bijective XCD chunking (2000 % 8 == 0), mblk-fastest: 8 consecutive
  // blocks share one 1 MB W panel (L2-hot); W streams HBM once; A in LLC.
  const int gid = blockIdx.x;
  const int swz = (gid & 7) * 250 + (gid >> 3);
  const int gemm = swz >= 1000;
  const int rem = swz - gemm * 1000;
  const int vblk = rem >> 3, mblk = rem & 7;
  const short* A = gemm ? At : As;
  const short* W = gemm ? Wt : Ws;
  unsigned long long* Lp = gemm ? Lgt : Lgs;
  const int m0 = mblk * 256, v0 = vblk * 256;

  const int tid = threadIdx.x;
  const int wave = tid >> 6, lane = tid & 63;
  const int lrow = lane & 15, lk = lane >> 4, lr7 = lrow & 7;
  const int wr = wave >> 2, wc = wave & 3;   // 2M x 4N wave grid
  const int wbase = wave * 512;              // gload LDS granule base (shorts)
  const int aro = (wr * 128 + lrow) * 64;    // A ds_read row base (shorts)
  const int bro = ASH + (wc * 64 + lrow) * 64;
  const char* Aby = (const char*)A;
  const char* Wby = (const char*)W;

  // Pre-swizzled per-lane global source offsets (bytes) for the 8 loads of a
  // K-tile; per tile only kb (bytes, = t*128) advances.
  unsigned aoff0, aoff1, aoff2, aoff3, boff0, boff1, boff2, boff3;
  {
#define MKOFF(i, dstA, dstB)                                                   \
    {                                                                          \
      int g = (i) * 512 + wave * 64 + lane;                                    \
      int row = g >> 3, c8p = g & 7, col = (c8p ^ (row & 7)) << 3;             \
      dstA = (unsigned)((((m0) + row) * H_DIM + col) * 2);                     \
      dstB = (unsigned)((((v0) + row) * H_DIM + col) * 2);                     \
    }
    MKOFF(0, aoff0, boff0) MKOFF(1, aoff1, boff1)
    MKOFF(2, aoff2, boff2) MKOFF(3, aoff3, boff3)
#undef MKOFF
  }

  f32x4 acc[8][4];
#pragma unroll
  for (int i = 0; i < 8; ++i)
#pragma unroll
    for (int j = 0; j < 4; ++j) acc[i][j] = (f32x4){0.f, 0.f, 0.f, 0.f};
  short8 bv[4];

  // Prologue: tile0 fully + A-lo of tile1; vmcnt(2) leaves A0,A2(t1) in flight.
  STAGE_A(0, 0, 0); STAGE_A(2, 0, 0);
  STAGE_B(0, 0, 0); STAGE_B(1, 0, 0); STAGE_B(2, 0, 0); STAGE_B(3, 0, 0);
  STAGE_A(1, 0, 0); STAGE_A(3, 0, 0);
  STAGE_A(0, BUF_SH, 128); STAGE_A(2, BUF_SH, 128);
  asm volatile("s_waitcnt vmcnt(2)" ::: "memory");
  __builtin_amdgcn_s_barrier();

  // Steady tiles 0..29. Per tile t: P1 stages B0-3(t+1)->nxt, P2 stages
  // A1,A3(t+1)->nxt, P4 stages A0,A2(t+2)->cur (rows 0-63/128-191, last read
  // in P3) and gates vmcnt(2) (only A0,A2(t+2) left in flight).
  for (int t = 0; t < 30; ++t) {
    const int cbase = (t & 1) * BUF_SH, nbase = cbase ^ BUF_SH;
    const int kbn = (t + 1) * 128, kbc = (t + 2) * 128;
    PHASE(0, 0, -1, STAGE_B(0, nbase, kbn); STAGE_B(1, nbase, kbn);
                    STAGE_B(2, nbase, kbn); STAGE_B(3, nbase, kbn););
    PHASE(0, 1, -1, STAGE_A(1, nbase, kbn); STAGE_A(3, nbase, kbn););
    PHASE(1, 0, -1, (void)0;);
    PHASE(1, 1,  2, STAGE_A(0, cbase, kbc); STAGE_A(2, cbase, kbc););
  }
  // Tile 30: stage rest of tile 31, drain at end.
  { const int cbase = 0, nbase = BUF_SH, kbn = 31 * 128;
    PHASE(0, 0, -1, STAGE_B(0, nbase, kbn); STAGE_B(1, nbase, kbn);
                    STAGE_B(2, nbase, kbn); STAGE_B(3, nbase, kbn););
    PHASE(0, 1, -1, STAGE_A(1, nbase, kbn); STAGE_A(3, nbase, kbn););
    PHASE(1, 0, -1, (void)0;);
    PHASE(1, 1,  0, (void)0;);
  }
  // Tile 31: no staging, no gates.
  { const int cbase = BUF_SH;
    PHASE(0, 0, -1, (void)0;);
    PHASE(0, 1, -1, (void)0;);
    PHASE(1, 0, -1, (void)0;);
    PHASE(1, 1, -1, (void)0;);
  }

  // Epilogue: pack layout. 16x16 C/D: col=lane&15, row=(lane>>4)*4+j
  // (m89-verified) -> acc[fm][fn]'s 4 floats are 4 CONSECUTIVE rows at one
  // column. Pack them into one 8 B bf16 store, lane-consecutive (coalesced).
  // Pack semantic: pack p at (mblk,vblk,wave,fm,fn,q=lane>>4,c=lane&15)
  // holds rows mblk*256+wr*128+fm*16+q*4+{0..3}, col vblk*256+wc*64+fn*16+c.
  // index = (mblk*125+vblk)*16384 + wave*2048 + (fm*4+fn)*64 + lane.
  const size_t pkb = ((size_t)(mblk * 125 + vblk) * 8 + wave) * 2048 + lane;
  s16x4* Lp4 = (s16x4*)Lp;
#pragma unroll
  for (int fm = 0; fm < 8; ++fm)
#pragma unroll
    for (int fn = 0; fn < 4; ++fn) {
      s16x4 pk;
      pk[0] = f2b(acc[fm][fn][0]);
      pk[1] = f2b(acc[fm][fn][1]);
      pk[2] = f2b(acc[fm][fn][2]);
      pk[3] = f2b(acc[fm][fn][3]);
      Lp4[pkb + (fm * 4 + fn) * 64] = pk;
    }
}

// ---------------- fused logsumexp + JSD over the pack layout --------------
// Block g handles rows 4g..4g+3 (one pack's 4 rows). Row-group decomp:
// G = mblk*64 + wr*32 + fm*4 + q  ->  mblk=g>>6, wr=(g>>5)&1, fm=(g>>2)&7,
// q=g&3. Thread covers (wc=tid>>6, fn=(tid>>4)&3, c=tid&15) x vblk 0..124.
// No max subtraction: logits ~ N(0,1) (unit-variance dot), |logit| <~ 7,
// so sum(exp) <= 32000*e^7 ~ 3.5e7 — comfortably inside f32 (validated r4).
__global__ __launch_bounds__(256) void rows_jsd(
    const unsigned long long* __restrict__ Ls,
    const unsigned long long* __restrict__ Lt,
    float* __restrict__ partials) {
  const int g = blockIdx.x, tid = threadIdx.x;
  const int mblk = g >> 6, wr = (g >> 5) & 1, fm = (g >> 2) & 7, q = g & 3;
  const size_t base = (size_t)mblk * 2048000 + wr * 8192 + fm * 256 + q * 16;
  const int coff = (tid >> 6) * 2048 + ((tid >> 4) & 3) * 64 + (tid & 15);
  const unsigned long long* ps = Ls + base + coff;
  const unsigned long long* pt = Lt + base + coff;

  float ses[4] = {0.f, 0.f, 0.f, 0.f};
  float set[4] = {0.f, 0.f, 0.f, 0.f};
  for (int vb = 0; vb < 125; ++vb) {
    unsigned long long xs = ps[(size_t)vb * 16384];
    unsigned long long xt = pt[(size_t)vb * 16384];
#pragma unroll
    for (int j = 0; j < 4; ++j) {
      ses[j] += __expf(bf2f((short)(xs >> (16 * j))));
      set[j] += __expf(bf2f((short)(xt >> (16 * j))));
    }
  }
  __shared__ float red[8][4];
  __shared__ float zz[8];
  const int wv = tid >> 6, ln = tid & 63;
#pragma unroll
  for (int c = 0; c < 8; ++c) {
    float v = (c < 4) ? ses[c] : set[c - 4];
#pragma unroll
    for (int o = 32; o; o >>= 1) v += __shfl_xor(v, o);
    if (ln == 0) red[c][wv] = v;
  }
  __syncthreads();
  if (tid < 8) zz[tid] = __logf(red[tid][0] + red[tid][1] + red[tid][2] + red[tid][3]);
  __syncthreads();
  float zq[4], zp[4];
#pragma unroll
  for (int j = 0; j < 4; ++j) { zq[j] = zz[j]; zp[j] = zz[4 + j]; }

  float acc = 0.f;
  for (int vb = 0; vb < 125; ++vb) {
    unsigned long long xs = ps[(size_t)vb * 16384];
    unsigned long long xt = pt[(size_t)vb * 16384];
#pragma unroll
    for (int j = 0; j < 4; ++j) {
      float lq = bf2f((short)(xs >> (16 * j))) - zq[j];
      float lp = bf2f((short)(xt >> (16 * j))) - zp[j];
      float qq = __expf(lq), pp = __expf(lp);
      float mm = pp + 0.5f * (qq - pp);
      float lm = __logf(mm);
      acc += 0.5f * (pp * (lp - lm)) + 0.5f * (qq * (lq - lm));
    }
  }
#pragma unroll
  for (int o = 32; o; o >>= 1) acc += __shfl_xor(acc, o);
  if (ln == 0) red[0][wv] = acc;
  __syncthreads();
  if (tid == 0) partials[g] = red[0][0] + red[0][1] + red[0][2] + red[0][3];
}

__global__ __launch_bounds__(256) void final_reduce(const float* __restrict__ partials,
                                                    int nb, float* __restrict__ out) {
  float s = 0.f;
  for (int i = threadIdx.x; i < nb; i += 256) s += partials[i];
#pragma unroll
  for (int o = 32; o; o >>= 1) s += __shfl_xor(s, o);
  __shared__ float red[4];
  if ((threadIdx.x & 63) == 0) red[threadIdx.x >> 6] = s;
  __syncthreads();
  if (threadIdx.x == 0) out[0] = (red[0] + red[1] + red[2] + red[3]) / (float)N_TOK;
}

// ---------------- launch ---------------------------------------------------
extern "C" void kernel_launch(void* const* d_in, const int* in_sizes, int n_in,
                              void* d_out, int out_size, void* d_ws, size_t ws_size,
                              hipStream_t stream) {
  const float* s_in = (const float*)d_in[0];
  const float* t_in = (const float*)d_in[1];
  const float* w_s  = (const float*)d_in[2];
  const float* w_t  = (const float*)d_in[3];
  float* out = (float*)d_out;

  char* ws = (char*)d_ws;
  size_t off = 0;
  auto alloc = [&](size_t bytes) {
    char* p = ws + off;
    off += (bytes + 255) & ~(size_t)255;
    return p;
  };
  short* Abf_s = (short*)alloc((size_t)N_TOK * H_DIM * 2);
  short* Abf_t = (short*)alloc((size_t)N_TOK * H_DIM * 2);
  short* Wbf_s = (short*)alloc((size_t)V_DIM * H_DIM * 2);
  short* Wbf_t = (short*)alloc((size_t)V_DIM * H_DIM * 2);
  unsigned long long* Lg_s = (unsigned long long*)alloc((size_t)N_TOK * V_DIM * 2);
  unsigned long long* Lg_t = (unsigned long long*)alloc((size_t)N_TOK * V_DIM * 2);
  float* partials = (float*)alloc(512 * 4);

  if (off > ws_size) {
    hipMemsetAsync(d_out, 0xFF, sizeof(float), stream);
    return;
  }

  cvt_bf16<<<512, 256, 0, stream>>>(s_in, Abf_s, N_TOK * H_DIM / 8);
  cvt_bf16<<<512, 256, 0, stream>>>(t_in, Abf_t, N_TOK * H_DIM / 8);
  cvt_bf16<<<2048, 256, 0, stream>>>(w_s, Wbf_s, V_DIM * H_DIM / 8);
  cvt_bf16<<<2048, 256, 0, stream>>>(w_t, Wbf_t, V_DIM * H_DIM / 8);

  gemm_logits<<<2000, 512, 0, stream>>>(Abf_s, Abf_t, Wbf_s, Wbf_t, Lg_s, Lg_t);

  rows_jsd<<<512, 256, 0, stream>>>(Lg_s, Lg_t, partials);
  final_reduce<<<1, 256, 0, stream>>>(partials, 512, out);
}

// Round 6
// 751.602 us; speedup vs baseline: 1.0828x; 1.0229x over previous
//
#include <hip/hip_runtime.h>
#include <hip/hip_bf16.h>

#define N_TOK 2048
#define H_DIM 2048
#define V_DIM 32000

typedef __attribute__((ext_vector_type(8))) short short8;
typedef __attribute__((ext_vector_type(4))) short s16x4;
typedef __attribute__((ext_vector_type(4))) float f32x4;

__device__ __forceinline__ float bf2f(short s) {
  unsigned int u = ((unsigned int)(unsigned short)s) << 16;
  return __uint_as_float(u);
}
__device__ __forceinline__ short f2b(float f) {
  __hip_bfloat16 h = __float2bfloat16(f);
  return *reinterpret_cast<short*>(&h);
}

// ---------------- fp32 -> bf16 conversion (vectorized, grid-stride) -------
__global__ __launch_bounds__(256) void cvt_bf16(const float* __restrict__ s,
                                                short* __restrict__ d, int n8) {
  int stride = gridDim.x * 256;
  for (int i = blockIdx.x * 256 + threadIdx.x; i < n8; i += stride) {
    const float4* sp = reinterpret_cast<const float4*>(s) + (size_t)i * 2;
    float4 a = sp[0], b = sp[1];
    short8 o;
    o[0] = f2b(a.x); o[1] = f2b(a.y); o[2] = f2b(a.z); o[3] = f2b(a.w);
    o[4] = f2b(b.x); o[5] = f2b(b.y); o[6] = f2b(b.z); o[7] = f2b(b.w);
    *reinterpret_cast<short8*>(d + (size_t)i * 8) = o;
  }
}

// ---------------- bf16 GEMM: logits[n,v] = sum_h A[n,h]*W[v,h] ------------
// BM=BN=256, BK=64, 8 waves (2M x 4N), wave tile 128x64, MFMA 16x16x32
// (round-3/5 fragment pattern: 0 LDS bank conflicts).
// NEW (r6): only TWO block barriers per K-tile. Region1 = phases
// (KK0,MH0)+(KK0,MH1)+(KK1,MH0) with staging of tile t+1 (B, A-hi) into
// nbase only — reads touch cbase, writes touch nbase => no internal
// barriers; compiler free-schedules reads ahead of MFMAs. Mid-barrier, then
// Region2 = (KK1,MH1) + staging A-lo(t+2) into cbase (rows 0-63/128-191,
// fully read by end of P3 which the mid-barrier publishes), counted
// vmcnt(2) gate, end barrier.
#define ASH 16384      // A shorts per buffer (256 rows x 64 cols)
#define BUF_SH 32768   // shorts per buffer (A + B)

__device__ __forceinline__ void gload_lds16(const void* g, void* l) {
  __builtin_amdgcn_global_load_lds(
      (const __attribute__((address_space(1))) void*)g,
      (__attribute__((address_space(3))) void*)l, 16, 0, 0);
}

#define STAGE_A(i, dst, kb) \
  gload_lds16(Aby + aoff##i + (kb), &lds[(dst) + (i) * 4096 + wbase])
#define STAGE_B(i, dst, kb) \
  gload_lds16(Wby + boff##i + (kb), &lds[(dst) + ASH + (i) * 4096 + wbase])

// One compute phase: ds_read fragments + 16 MFMA. No asm — compiler inserts
// its own lgkmcnt between ds_read and dependent MFMA and may pipeline across
// phases within a region.
#define COMPUTE_PHASE(KK, MH) do {                                             \
    const int xorc = (((KK) * 4 + lk) ^ lr7) << 3;                             \
    short8 av0 = *(const short8*)&lds[cbase + aro + (MH)*4096 + 0    + xorc];  \
    short8 av1 = *(const short8*)&lds[cbase + aro + (MH)*4096 + 1024 + xorc];  \
    short8 av2 = *(const short8*)&lds[cbase + aro + (MH)*4096 + 2048 + xorc];  \
    short8 av3 = *(const short8*)&lds[cbase + aro + (MH)*4096 + 3072 + xorc];  \
    if ((MH) == 0) {                                                           \
      bv[0] = *(const short8*)&lds[cbase + bro + 0    + xorc];                 \
      bv[1] = *(const short8*)&lds[cbase + bro + 1024 + xorc];                 \
      bv[2] = *(const short8*)&lds[cbase + bro + 2048 + xorc];                 \
      bv[3] = *(const short8*)&lds[cbase + bro + 3072 + xorc];                 \
    }                                                                          \
    acc[(MH)*4+0][0] = __builtin_amdgcn_mfma_f32_16x16x32_bf16(av0, bv[0], acc[(MH)*4+0][0],0,0,0); \
    acc[(MH)*4+0][1] = __builtin_amdgcn_mfma_f32_16x16x32_bf16(av0, bv[1], acc[(MH)*4+0][1],0,0,0); \
    acc[(MH)*4+0][2] = __builtin_amdgcn_mfma_f32_16x16x32_bf16(av0, bv[2], acc[(MH)*4+0][2],0,0,0); \
    acc[(MH)*4+0][3] = __builtin_amdgcn_mfma_f32_16x16x32_bf16(av0, bv[3], acc[(MH)*4+0][3],0,0,0); \
    acc[(MH)*4+1][0] = __builtin_amdgcn_mfma_f32_16x16x32_bf16(av1, bv[0], acc[(MH)*4+1][0],0,0,0); \
    acc[(MH)*4+1][1] = __builtin_amdgcn_mfma_f32_16x16x32_bf16(av1, bv[1], acc[(MH)*4+1][1],0,0,0); \
    acc[(MH)*4+1][2] = __builtin_amdgcn_mfma_f32_16x16x32_bf16(av1, bv[2], acc[(MH)*4+1][2],0,0,0); \
    acc[(MH)*4+1][3] = __builtin_amdgcn_mfma_f32_16x16x32_bf16(av1, bv[3], acc[(MH)*4+1][3],0,0,0); \
    acc[(MH)*4+2][0] = __builtin_amdgcn_mfma_f32_16x16x32_bf16(av2, bv[0], acc[(MH)*4+2][0],0,0,0); \
    acc[(MH)*4+2][1] = __builtin_amdgcn_mfma_f32_16x16x32_bf16(av2, bv[1], acc[(MH)*4+2][1],0,0,0); \
    acc[(MH)*4+2][2] = __builtin_amdgcn_mfma_f32_16x16x32_bf16(av2, bv[2], acc[(MH)*4+2][2],0,0,0); \
    acc[(MH)*4+2][3] = __builtin_amdgcn_mfma_f32_16x16x32_bf16(av2, bv[3], acc[(MH)*4+2][3],0,0,0); \
    acc[(MH)*4+3][0] = __builtin_amdgcn_mfma_f32_16x16x32_bf16(av3, bv[0], acc[(MH)*4+3][0],0,0,0); \
    acc[(MH)*4+3][1] = __builtin_amdgcn_mfma_f32_16x16x32_bf16(av3, bv[1], acc[(MH)*4+3][1],0,0,0); \
    acc[(MH)*4+3][2] = __builtin_amdgcn_mfma_f32_16x16x32_bf16(av3, bv[2], acc[(MH)*4+3][2],0,0,0); \
    acc[(MH)*4+3][3] = __builtin_amdgcn_mfma_f32_16x16x32_bf16(av3, bv[3], acc[(MH)*4+3][3],0,0,0); \
  } while (0)

__global__ __launch_bounds__(512, 2) void gemm_logits(
    const short* __restrict__ As, const short* __restrict__ At,
    const short* __restrict__ Ws, const short* __restrict__ Wt,
    unsigned long long* __restrict__ Lgs, unsigned long long* __restrict__ Lgt,
    float* __restrict__ Zpart) {
  __shared__ short lds[2 * BUF_SH];  // 128 KiB

  // Bijective XCD chunking (2000 % 8 == 0), mblk-fastest: 8 consecutive
  // blocks share one 1 MB W panel (L2-hot); W streams HBM once; A in LLC.
  const int gid = blockIdx.x;
  const int swz = (gid & 7) * 250 + (gid >> 3);
  const int gemm = swz >= 1000;
  const int rem = swz - gemm * 1000;
  const int vblk = rem >> 3, mblk = rem & 7;
  const short* A = gemm ? At : As;
  const short* W = gemm ? Wt : Ws;
  unsigned long long* Lp = gemm ? Lgt : Lgs;
  const int m0 = mblk * 256, v0 = vblk * 256;

  const int tid = threadIdx.x;
  const int wave = tid >> 6, lane = tid & 63;
  const int lrow = lane & 15, lk = lane >> 4, lr7 = lrow & 7;
  const int wr = wave >> 2, wc = wave & 3;   // 2M x 4N wave grid
  const int wbase = wave * 512;              // gload LDS granule base (shorts)
  const int aro = (wr * 128 + lrow) * 64;    // A ds_read row base (shorts)
  const int bro = ASH + (wc * 64 + lrow) * 64;
  const char* Aby = (const char*)A;
  const char* Wby = (const char*)W;

  // Pre-swizzled per-lane global source offsets (bytes) for the 8 loads of a
  // K-tile; per tile only kb (bytes, = t*128) advances.
  unsigned aoff0, aoff1, aoff2, aoff3, boff0, boff1, boff2, boff3;
  {
#define MKOFF(i, dstA, dstB)                                                   \
    {                                                                          \
      int g = (i) * 512 + wave * 64 + lane;                                    \
      int row = g >> 3, c8p = g & 7, col = (c8p ^ (row & 7)) << 3;             \
      dstA = (unsigned)((((m0) + row) * H_DIM + col) * 2);                     \
      dstB = (unsigned)((((v0) + row) * H_DIM + col) * 2);                     \
    }
    MKOFF(0, aoff0, boff0) MKOFF(1, aoff1, boff1)
    MKOFF(2, aoff2, boff2) MKOFF(3, aoff3, boff3)
#undef MKOFF
  }

  f32x4 acc[8][4];
#pragma unroll
  for (int i = 0; i < 8; ++i)
#pragma unroll
    for (int j = 0; j < 4; ++j) acc[i][j] = (f32x4){0.f, 0.f, 0.f, 0.f};
  short8 bv[4];

  // Prologue: tile0 fully (8 loads) + A-lo of tile1 (2). vmcnt(2) leaves
  // A0,A2(t1) in flight — the steady-state invariant at every tile gate.
  STAGE_A(0, 0, 0); STAGE_A(2, 0, 0);
  STAGE_B(0, 0, 0); STAGE_B(1, 0, 0); STAGE_B(2, 0, 0); STAGE_B(3, 0, 0);
  STAGE_A(1, 0, 0); STAGE_A(3, 0, 0);
  STAGE_A(0, BUF_SH, 128); STAGE_A(2, BUF_SH, 128);
  asm volatile("s_waitcnt vmcnt(2)" ::: "memory");
  __builtin_amdgcn_sched_barrier(0);
  __builtin_amdgcn_s_barrier();

  // Steady tiles 0..29.
  for (int t = 0; t < 30; ++t) {
    const int cbase = (t & 1) * BUF_SH, nbase = cbase ^ BUF_SH;
    const int kbn = (t + 1) * 128, kbc = (t + 2) * 128;
    // Region 1: stage t+1's B + A-hi into nbase; compute 3 phases on cbase.
    STAGE_B(0, nbase, kbn); STAGE_B(1, nbase, kbn);
    STAGE_B(2, nbase, kbn); STAGE_B(3, nbase, kbn);
    STAGE_A(1, nbase, kbn); STAGE_A(3, nbase, kbn);
    COMPUTE_PHASE(0, 0);
    COMPUTE_PHASE(0, 1);
    COMPUTE_PHASE(1, 0);
    __builtin_amdgcn_s_barrier();
    // Region 2: stage A-lo(t+2) into cbase (rows fully read after P3),
    // compute last phase, counted gate, publish.
    STAGE_A(0, cbase, kbc); STAGE_A(2, cbase, kbc);
    COMPUTE_PHASE(1, 1);
    asm volatile("s_waitcnt vmcnt(2)" ::: "memory");
    __builtin_amdgcn_sched_barrier(0);
    __builtin_amdgcn_s_barrier();
  }
  // Tile 30: stage rest of tile 31; drain fully at the gate.
  {
    const int cbase = 0, nbase = BUF_SH, kbn = 31 * 128;
    STAGE_B(0, nbase, kbn); STAGE_B(1, nbase, kbn);
    STAGE_B(2, nbase, kbn); STAGE_B(3, nbase, kbn);
    STAGE_A(1, nbase, kbn); STAGE_A(3, nbase, kbn);
    COMPUTE_PHASE(0, 0);
    COMPUTE_PHASE(0, 1);
    COMPUTE_PHASE(1, 0);
    __builtin_amdgcn_s_barrier();
    COMPUTE_PHASE(1, 1);
    asm volatile("s_waitcnt vmcnt(0)" ::: "memory");
    __builtin_amdgcn_sched_barrier(0);
    __builtin_amdgcn_s_barrier();
  }
  // Tile 31: pure compute.
  {
    const int cbase = BUF_SH;
    COMPUTE_PHASE(0, 0);
    COMPUTE_PHASE(0, 1);
    COMPUTE_PHASE(1, 0);
    COMPUTE_PHASE(1, 1);
  }

  // ---- Epilogue A: per-row sum-of-exp over this wave's 64 columns --------
  // 16x16 C/D: col=lane&15, row=(lane>>4)*4+j. Lanes c=0..15 of each
  // 16-lane group (fixed q=lane>>4) hold the same 4 rows per fm; reduce
  // exp-sums across c with shfl_xor masks 8,4,2,1 (stay inside the group).
  {
    const int q = lane >> 4;
    const int zb = (gemm * 2048 + mblk * 256 + wr * 128) * 500 + vblk * 4 + wc;
#pragma unroll
    for (int fm = 0; fm < 8; ++fm) {
#pragma unroll
      for (int j = 0; j < 4; ++j) {
        float s = __expf(acc[fm][0][j]) + __expf(acc[fm][1][j]) +
                  __expf(acc[fm][2][j]) + __expf(acc[fm][3][j]);
        s += __shfl_xor(s, 8);
        s += __shfl_xor(s, 4);
        s += __shfl_xor(s, 2);
        s += __shfl_xor(s, 1);
        if ((lane & 15) == 0)
          Zpart[zb + (fm * 16 + q * 4 + j) * 500] = s;
      }
    }
  }

  // ---- Epilogue B: pack-layout bf16 logits store (r5-verified) -----------
  // index = ((mblk*125+vblk)*8 + wave)*2048 + (fm*4+fn)*64 + lane.
  const size_t pkb = ((size_t)(mblk * 125 + vblk) * 8 + wave) * 2048 + lane;
  s16x4* Lp4 = (s16x4*)Lp;
#pragma unroll
  for (int fm = 0; fm < 8; ++fm)
#pragma unroll
    for (int fn = 0; fn < 4; ++fn) {
      s16x4 pk;
      pk[0] = f2b(acc[fm][fn][0]);
      pk[1] = f2b(acc[fm][fn][1]);
      pk[2] = f2b(acc[fm][fn][2]);
      pk[3] = f2b(acc[fm][fn][3]);
      Lp4[pkb + (fm * 4 + fn) * 64] = pk;
    }
}

// ---------------- Z reduction: Z[r] = log(sum_cb Zpart[r][cb]) ------------
// 4096 rows (student 0..2047, teacher 2048..4095), 500 partials each.
__global__ __launch_bounds__(256) void zred(const float* __restrict__ Zpart,
                                            float* __restrict__ Z) {
  const int tid = threadIdx.x;
  const int row = blockIdx.x * 64 + (tid >> 2);
  const int part = tid & 3;
  const float* p = Zpart + (size_t)row * 500 + part;
  float s = 0.f;
#pragma unroll 5
  for (int i = 0; i < 125; ++i) s += p[i * 4];
  s += __shfl_xor(s, 1);
  s += __shfl_xor(s, 2);
  if (part == 0) Z[row] = __logf(s);
}

// ---------------- single-pass JSD over the pack layout --------------------
// Block g handles rows 4g..4g+3. Decomp: mblk=g>>6, wr=(g>>5)&1, fm=(g>>2)&7,
// q=g&3 (r5-verified indexing). Z provides the logsumexp (no-max exp safe:
// logits ~N(0,1), sum(exp) <= 32000*e^7 — validated rounds 4-5).
__global__ __launch_bounds__(256) void rows_jsd(
    const unsigned long long* __restrict__ Ls,
    const unsigned long long* __restrict__ Lt,
    const float* __restrict__ Z,
    float* __restrict__ partials) {
  const int g = blockIdx.x, tid = threadIdx.x;
  const int mblk = g >> 6, wr = (g >> 5) & 1, fm = (g >> 2) & 7, q = g & 3;
  const int row0 = mblk * 256 + wr * 128 + fm * 16 + q * 4;
  const size_t base = (size_t)mblk * 2048000 + wr * 8192 + fm * 256 + q * 16;
  const int coff = (tid >> 6) * 2048 + ((tid >> 4) & 3) * 64 + (tid & 15);
  const unsigned long long* ps = Ls + base + coff;
  const unsigned long long* pt = Lt + base + coff;

  float zq[4], zp[4];
#pragma unroll
  for (int j = 0; j < 4; ++j) {
    zq[j] = Z[row0 + j];
    zp[j] = Z[2048 + row0 + j];
  }

  float acc = 0.f;
  for (int vb = 0; vb < 125; ++vb) {
    unsigned long long xs = ps[(size_t)vb * 16384];
    unsigned long long xt = pt[(size_t)vb * 16384];
#pragma unroll
    for (int j = 0; j < 4; ++j) {
      float lq = bf2f((short)(xs >> (16 * j))) - zq[j];
      float lp = bf2f((short)(xt >> (16 * j))) - zp[j];
      float qq = __expf(lq), pp = __expf(lp);
      float mm = pp + 0.5f * (qq - pp);
      float lm = __logf(mm);
      acc += 0.5f * (pp * (lp - lm)) + 0.5f * (qq * (lq - lm));
    }
  }
#pragma unroll
  for (int o = 32; o; o >>= 1) acc += __shfl_xor(acc, o);
  __shared__ float red[4];
  const int wv = tid >> 6, ln = tid & 63;
  if (ln == 0) red[wv] = acc;
  __syncthreads();
  if (tid == 0) partials[g] = red[0] + red[1] + red[2] + red[3];
}

__global__ __launch_bounds__(256) void final_reduce(const float* __restrict__ partials,
                                                    int nb, float* __restrict__ out) {
  float s = 0.f;
  for (int i = threadIdx.x; i < nb; i += 256) s += partials[i];
#pragma unroll
  for (int o = 32; o; o >>= 1) s += __shfl_xor(s, o);
  __shared__ float red[4];
  if ((threadIdx.x & 63) == 0) red[threadIdx.x >> 6] = s;
  __syncthreads();
  if (threadIdx.x == 0) out[0] = (red[0] + red[1] + red[2] + red[3]) / (float)N_TOK;
}

// ---------------- launch ---------------------------------------------------
extern "C" void kernel_launch(void* const* d_in, const int* in_sizes, int n_in,
                              void* d_out, int out_size, void* d_ws, size_t ws_size,
                              hipStream_t stream) {
  const float* s_in = (const float*)d_in[0];
  const float* t_in = (const float*)d_in[1];
  const float* w_s  = (const float*)d_in[2];
  const float* w_t  = (const float*)d_in[3];
  float* out = (float*)d_out;

  char* ws = (char*)d_ws;
  size_t off = 0;
  auto alloc = [&](size_t bytes) {
    char* p = ws + off;
    off += (bytes + 255) & ~(size_t)255;
    return p;
  };
  short* Abf_s = (short*)alloc((size_t)N_TOK * H_DIM * 2);
  short* Abf_t = (short*)alloc((size_t)N_TOK * H_DIM * 2);
  short* Wbf_s = (short*)alloc((size_t)V_DIM * H_DIM * 2);
  short* Wbf_t = (short*)alloc((size_t)V_DIM * H_DIM * 2);
  unsigned long long* Lg_s = (unsigned long long*)alloc((size_t)N_TOK * V_DIM * 2);
  unsigned long long* Lg_t = (unsigned long long*)alloc((size_t)N_TOK * V_DIM * 2);
  float* Zpart = (float*)alloc((size_t)2 * 2048 * 500 * 4);
  float* Z     = (float*)alloc(4096 * 4);
  float* partials = (float*)alloc(512 * 4);

  if (off > ws_size) {
    hipMemsetAsync(d_out, 0xFF, sizeof(float), stream);
    return;
  }

  cvt_bf16<<<512, 256, 0, stream>>>(s_in, Abf_s, N_TOK * H_DIM / 8);
  cvt_bf16<<<512, 256, 0, stream>>>(t_in, Abf_t, N_TOK * H_DIM / 8);
  cvt_bf16<<<2048, 256, 0, stream>>>(w_s, Wbf_s, V_DIM * H_DIM / 8);
  cvt_bf16<<<2048, 256, 0, stream>>>(w_t, Wbf_t, V_DIM * H_DIM / 8);

  gemm_logits<<<2000, 512, 0, stream>>>(Abf_s, Abf_t, Wbf_s, Wbf_t,
                                        Lg_s, Lg_t, Zpart);

  zred<<<64, 256, 0, stream>>>(Zpart, Z);
  rows_jsd<<<512, 256, 0, stream>>>(Lg_s, Lg_t, Z, partials);
  final_reduce<<<1, 256, 0, stream>>>(partials, 512, out);
}